// Round 2
// baseline (1146.024 us; speedup 1.0000x reference)
//
#include <hip/hip_runtime.h>

// GCN 2-layer, single persistent mega-kernel (R2).
// K0 clear+wprep (separate tiny launch) -> MEGA: [P1-bucket | gemm1] -> gridbar ->
// per-bucket CSR+dinv+pad -> gridbar -> agg128(+bias,relu) -> gridbar ->
// gemm2(*dinv) -> gridbar -> agg64(+bias) -> d_out.
// Grid barriers: generation-based, agent-scope atomics + __threadfence (cross-XCD
// L2 wb/inv). Grid = 1024 = 4 blocks/CU co-resident via __launch_bounds__(256,4)
// (LDS 34KB*4=136<=160KB, VGPR<=128). Bounded spin guard: fail, never hang.

#define TPB 256
#define NBKT 196        // ceil(50000/256) buckets of 256 nodes
#define EB_CAP 4608     // edge-buffer slots per bucket (mean 4096 + 8 sigma)
#define CSR_CAP 6400    // 4608 + 256*7 pad-to-8 worst case
#define P1_EPB 8192     // edges per P1 block
#define GRID_BLKS 1024  // 4 blocks/CU on 256 CUs; co-residency required

typedef __bf16 bf16x8 __attribute__((ext_vector_type(8)));
typedef __bf16 bf16x4 __attribute__((ext_vector_type(4)));
typedef __bf16 bf16x2 __attribute__((ext_vector_type(2)));
typedef float f32x4 __attribute__((ext_vector_type(4)));

__device__ __forceinline__ float bflo(unsigned u) { return __uint_as_float(u << 16); }
__device__ __forceinline__ float bfhi(unsigned u) { return __uint_as_float(u & 0xffff0000u); }

// ---------------- device-scope grid barrier (all blocks co-resident) ----------------
__device__ __forceinline__ void grid_bar(unsigned* cnt, unsigned* gen, unsigned nblk) {
    __syncthreads();
    if (threadIdx.x == 0) {
        unsigned g = __hip_atomic_load(gen, __ATOMIC_RELAXED, __HIP_MEMORY_SCOPE_AGENT);
        __threadfence();  // release: write back this XCD's L2 (block stores drained by syncthreads)
        unsigned a = __hip_atomic_fetch_add(cnt, 1u, __ATOMIC_ACQ_REL, __HIP_MEMORY_SCOPE_AGENT);
        if (a == nblk - 1u) {
            __hip_atomic_store(cnt, 0u, __ATOMIC_RELAXED, __HIP_MEMORY_SCOPE_AGENT);
            __hip_atomic_fetch_add(gen, 1u, __ATOMIC_RELEASE, __HIP_MEMORY_SCOPE_AGENT);
        } else {
            int guard = 0;
            while (__hip_atomic_load(gen, __ATOMIC_ACQUIRE, __HIP_MEMORY_SCOPE_AGENT) == g) {
                __builtin_amdgcn_s_sleep(2);
                if (++guard > (1 << 22)) break;  // fail-safe: wrong answer beats a hang
            }
        }
        __threadfence();  // acquire: invalidate L1/L2 so post-barrier reads are fresh
    }
    __syncthreads();
}

// ---------------- K0: clear gcnt+barrier, zero sentinel rows, W frag pack ----------------
// A-frag (16x16x32): lane L holds A[m=L&15][k=(L>>4)*8+j]; A[m][k]=W[k][oct*16+m].
__global__ __launch_bounds__(256) void clear_wprep_kernel(
    unsigned* __restrict__ gcnt, float* __restrict__ dinv, __bf16* __restrict__ h2s,
    int N, unsigned* __restrict__ bar,
    const float* __restrict__ W1, const float* __restrict__ W2,
    __bf16* __restrict__ wf1, __bf16* __restrict__ wf2) {
    if (blockIdx.x == 0) {
        int t = threadIdx.x;
        if (t < NBKT) gcnt[t] = 0;
        if (t == 0) { dinv[N] = 0.0f; bar[0] = 0u; bar[1] = 0u; }   // sentinel + barrier state
        if (t < 32) ((unsigned*)(h2s + (long)N * 64))[t] = 0u;      // sentinel row = 0
        return;
    }
    int g = (blockIdx.x - 1) * TPB + threadIdx.x;
    if (g < 64 * 64) {  // W1: K=256 (8 ksteps), OC=128 (8 octiles)
        int frag = g >> 6, L = g & 63;
        int kstep = frag >> 3, oct = frag & 7;
        int oc = oct * 16 + (L & 15);
        int k0 = kstep * 32 + (L >> 4) * 8;
        bf16x8 v;
#pragma unroll
        for (int j = 0; j < 8; j++) v[j] = (__bf16)W1[(k0 + j) * 128 + oc];
        ((bf16x8*)wf1)[g] = v;
    } else if (g < 64 * 64 + 16 * 64) {  // W2: K=128 (4), OC=64 (4)
        int g2 = g - 64 * 64;
        int frag = g2 >> 6, L = g2 & 63;
        int kstep = frag >> 2, oct = frag & 3;
        int oc = oct * 16 + (L & 15);
        int k0 = kstep * 32 + (L >> 4) * 8;
        bf16x8 v;
#pragma unroll
        for (int j = 0; j < 8; j++) v[j] = (__bf16)W2[(k0 + j) * 64 + oc];
        ((bf16x8*)wf2)[g2] = v;
    }
}

// ---------------- MFMA GEMM body ----------------
// out[r][oc] = (sum_k A[r][k]*W[k][oc]) * (SCALE ? dinv[r] : 1), bf16 out. Wave: 32 rows.
template <bool IN_BF16, int K, int OC, bool SCALE>
__device__ __forceinline__ void gemm_body(int bid, int tid, const void* __restrict__ Ain,
                                          const bf16x8* __restrict__ wfrag,
                                          const float* __restrict__ dinv,
                                          __bf16* __restrict__ outp, int M) {
    constexpr int KS = K / 32, OT = OC / 16;
    int wave = tid >> 6, lane = tid & 63;
    int col = lane & 15, q = lane >> 4;
    long rb = (long)bid * 128 + wave * 32;
    long r0 = rb + col, r1 = rb + 16 + col;
    long r0c = (r0 < M) ? r0 : (M - 1);
    long r1c = (r1 < M) ? r1 : (M - 1);

    f32x4 acc[OT][2];
#pragma unroll
    for (int o = 0; o < OT; o++) {
        acc[o][0] = (f32x4){0.f, 0.f, 0.f, 0.f};
        acc[o][1] = (f32x4){0.f, 0.f, 0.f, 0.f};
    }

#pragma unroll
    for (int ks = 0; ks < KS; ks++) {
        int k0 = ks * 32 + q * 8;
        bf16x8 b0, b1;
        if constexpr (IN_BF16) {
            const __bf16* A = (const __bf16*)Ain;
            b0 = *(const bf16x8*)(A + r0c * K + k0);
            b1 = *(const bf16x8*)(A + r1c * K + k0);
        } else {
            const float* A = (const float*)Ain;
            float4 f0a = *(const float4*)(A + r0c * K + k0);
            float4 f0b = *(const float4*)(A + r0c * K + k0 + 4);
            float4 f1a = *(const float4*)(A + r1c * K + k0);
            float4 f1b = *(const float4*)(A + r1c * K + k0 + 4);
            b0[0] = (__bf16)f0a.x; b0[1] = (__bf16)f0a.y; b0[2] = (__bf16)f0a.z; b0[3] = (__bf16)f0a.w;
            b0[4] = (__bf16)f0b.x; b0[5] = (__bf16)f0b.y; b0[6] = (__bf16)f0b.z; b0[7] = (__bf16)f0b.w;
            b1[0] = (__bf16)f1a.x; b1[1] = (__bf16)f1a.y; b1[2] = (__bf16)f1a.z; b1[3] = (__bf16)f1a.w;
            b1[4] = (__bf16)f1b.x; b1[5] = (__bf16)f1b.y; b1[6] = (__bf16)f1b.z; b1[7] = (__bf16)f1b.w;
        }
#pragma unroll
        for (int ot = 0; ot < OT; ot++) {
            bf16x8 a = wfrag[(ks * OT + ot) * 64 + lane];
            acc[ot][0] = __builtin_amdgcn_mfma_f32_16x16x32_bf16(a, b0, acc[ot][0], 0, 0, 0);
            acc[ot][1] = __builtin_amdgcn_mfma_f32_16x16x32_bf16(a, b1, acc[ot][1], 0, 0, 0);
        }
    }

    float sc0 = 1.f, sc1 = 1.f;
    if constexpr (SCALE) {
        sc0 = dinv[r0c];
        sc1 = dinv[r1c];
    }
#pragma unroll
    for (int ot = 0; ot < OT; ot++) {
        int oc = ot * 16 + q * 4;
        if (r0 < M) {
            bf16x4 v;
#pragma unroll
            for (int r = 0; r < 4; r++) v[r] = (__bf16)(acc[ot][0][r] * sc0);
            *(bf16x4*)(outp + r0 * OC + oc) = v;
        }
        if (r1 < M) {
            bf16x4 v;
#pragma unroll
            for (int r = 0; r < 4; r++) v[r] = (__bf16)(acc[ot][1][r] * sc1);
            *(bf16x4*)(outp + r1 * OC + oc) = v;
        }
    }
}

// ---------------- agg128 per-node body (R1 pipelined, scalarized) ----------------
#define ACC8()                                             \
    do {                                                   \
        a0x += bflo(v0) * w0; a0y += bfhi(v0) * w0;        \
        a1x += bflo(v1) * w1; a1y += bfhi(v1) * w1;        \
        a2x += bflo(v2) * w2; a2y += bfhi(v2) * w2;        \
        a3x += bflo(v3) * w3; a3y += bfhi(v3) * w3;        \
        a0x += bflo(v4) * w4; a0y += bfhi(v4) * w4;        \
        a1x += bflo(v5) * w5; a1y += bfhi(v5) * w5;        \
        a2x += bflo(v6) * w6; a2y += bfhi(v6) * w6;        \
        a3x += bflo(v7) * w7; a3y += bfhi(v7) * w7;        \
    } while (0)

__device__ __forceinline__ void agg128_node(int n, int lane, const __bf16* __restrict__ h,
                                            const int* __restrict__ csr,
                                            const int2* __restrict__ se,
                                            const float* __restrict__ dinv,
                                            const float* __restrict__ bias,
                                            __bf16* __restrict__ outp) {
    int2 s_e = se[n];
    int start = s_e.x, m = s_e.y - s_e.x;    // m % 8 == 0
    float dn = dinv[n];
    const unsigned* hp = (const unsigned*)h;  // 2 bf16/word, row stride 64 words
    const int* sl = csr + start;              // 32B-aligned
    unsigned self = hp[(long)n * 64 + lane];
    float a0x = bflo(self) * dn, a0y = bfhi(self) * dn;  // *dn again at end -> dinv^2
    float a1x = 0.f, a1y = 0.f, a2x = 0.f, a2y = 0.f, a3x = 0.f, a3y = 0.f;
    if (m > 0) {
        int4 c0 = *(const int4*)sl;
        int4 c1 = *(const int4*)(sl + 4);
        int i0 = __builtin_amdgcn_readfirstlane(c0.x);
        int i1 = __builtin_amdgcn_readfirstlane(c0.y);
        int i2 = __builtin_amdgcn_readfirstlane(c0.z);
        int i3 = __builtin_amdgcn_readfirstlane(c0.w);
        int i4 = __builtin_amdgcn_readfirstlane(c1.x);
        int i5 = __builtin_amdgcn_readfirstlane(c1.y);
        int i6 = __builtin_amdgcn_readfirstlane(c1.z);
        int i7 = __builtin_amdgcn_readfirstlane(c1.w);
        unsigned v0 = hp[(long)i0 * 64 + lane], v1 = hp[(long)i1 * 64 + lane];
        unsigned v2 = hp[(long)i2 * 64 + lane], v3 = hp[(long)i3 * 64 + lane];
        unsigned v4 = hp[(long)i4 * 64 + lane], v5 = hp[(long)i5 * 64 + lane];
        unsigned v6 = hp[(long)i6 * 64 + lane], v7 = hp[(long)i7 * 64 + lane];
        float w0 = dinv[i0], w1 = dinv[i1], w2 = dinv[i2], w3 = dinv[i3];
        float w4 = dinv[i4], w5 = dinv[i5], w6 = dinv[i6], w7 = dinv[i7];
        int4 d0 = *(const int4*)(sl + 8);   // safe over-read: csr is followed by se in ws
        int4 d1 = *(const int4*)(sl + 12);
        for (int j = 8; j < m; j += 8) {
            int t0 = __builtin_amdgcn_readfirstlane(d0.x);
            int t1 = __builtin_amdgcn_readfirstlane(d0.y);
            int t2 = __builtin_amdgcn_readfirstlane(d0.z);
            int t3 = __builtin_amdgcn_readfirstlane(d0.w);
            int t4 = __builtin_amdgcn_readfirstlane(d1.x);
            int t5 = __builtin_amdgcn_readfirstlane(d1.y);
            int t6 = __builtin_amdgcn_readfirstlane(d1.z);
            int t7 = __builtin_amdgcn_readfirstlane(d1.w);
            unsigned u0 = hp[(long)t0 * 64 + lane], u1 = hp[(long)t1 * 64 + lane];
            unsigned u2 = hp[(long)t2 * 64 + lane], u3 = hp[(long)t3 * 64 + lane];
            unsigned u4 = hp[(long)t4 * 64 + lane], u5 = hp[(long)t5 * 64 + lane];
            unsigned u6 = hp[(long)t6 * 64 + lane], u7 = hp[(long)t7 * 64 + lane];
            float q0 = dinv[t0], q1 = dinv[t1], q2 = dinv[t2], q3 = dinv[t3];
            float q4 = dinv[t4], q5 = dinv[t5], q6 = dinv[t6], q7 = dinv[t7];
            d0 = *(const int4*)(sl + j + 8);
            d1 = *(const int4*)(sl + j + 12);
            ACC8();
            v0 = u0; v1 = u1; v2 = u2; v3 = u3; v4 = u4; v5 = u5; v6 = u6; v7 = u7;
            w0 = q0; w1 = q1; w2 = q2; w3 = q3; w4 = q4; w5 = q5; w6 = q6; w7 = q7;
        }
        ACC8();
    }
    float2 bv = ((const float2*)bias)[lane];
    float ox = (a0x + a1x + a2x + a3x) * dn + bv.x;
    float oy = (a0y + a1y + a2y + a3y) * dn + bv.y;
    ox = fmaxf(ox, 0.f);
    oy = fmaxf(oy, 0.f);
    bf16x2 st = {(__bf16)ox, (__bf16)oy};
    ((bf16x2*)outp)[(long)n * 64 + lane] = st;
}
#undef ACC8

// ---------------- agg64 per-node body (h2s pre-scaled by dinv[row]) ----------------
#define ACC8B()                                                                            \
    do {                                                                                   \
        a0 += __uint_as_float((unsigned)v0 << 16); a1 += __uint_as_float((unsigned)v1 << 16); \
        a2 += __uint_as_float((unsigned)v2 << 16); a3 += __uint_as_float((unsigned)v3 << 16); \
        a0 += __uint_as_float((unsigned)v4 << 16); a1 += __uint_as_float((unsigned)v5 << 16); \
        a2 += __uint_as_float((unsigned)v6 << 16); a3 += __uint_as_float((unsigned)v7 << 16); \
    } while (0)

__device__ __forceinline__ void agg64_node(int n, int lane, const __bf16* __restrict__ hs,
                                           const int* __restrict__ csr,
                                           const int2* __restrict__ se,
                                           const float* __restrict__ dinv,
                                           const float* __restrict__ bias,
                                           float* __restrict__ outp) {
    int2 s_e = se[n];
    int start = s_e.x, m = s_e.y - s_e.x;    // m % 8 == 0
    float dn = dinv[n];
    const unsigned short* hp = (const unsigned short*)hs;  // row stride 64
    const int* sl = csr + start;
    float a0 = __uint_as_float(((unsigned)hp[(long)n * 64 + lane]) << 16);
    float a1 = 0.f, a2 = 0.f, a3 = 0.f;
    if (m > 0) {
        int4 c0 = *(const int4*)sl;
        int4 c1 = *(const int4*)(sl + 4);
        int i0 = __builtin_amdgcn_readfirstlane(c0.x);
        int i1 = __builtin_amdgcn_readfirstlane(c0.y);
        int i2 = __builtin_amdgcn_readfirstlane(c0.z);
        int i3 = __builtin_amdgcn_readfirstlane(c0.w);
        int i4 = __builtin_amdgcn_readfirstlane(c1.x);
        int i5 = __builtin_amdgcn_readfirstlane(c1.y);
        int i6 = __builtin_amdgcn_readfirstlane(c1.z);
        int i7 = __builtin_amdgcn_readfirstlane(c1.w);
        unsigned short v0 = hp[(long)i0 * 64 + lane], v1 = hp[(long)i1 * 64 + lane];
        unsigned short v2 = hp[(long)i2 * 64 + lane], v3 = hp[(long)i3 * 64 + lane];
        unsigned short v4 = hp[(long)i4 * 64 + lane], v5 = hp[(long)i5 * 64 + lane];
        unsigned short v6 = hp[(long)i6 * 64 + lane], v7 = hp[(long)i7 * 64 + lane];
        int4 d0 = *(const int4*)(sl + 8);
        int4 d1 = *(const int4*)(sl + 12);
        for (int j = 8; j < m; j += 8) {
            int t0 = __builtin_amdgcn_readfirstlane(d0.x);
            int t1 = __builtin_amdgcn_readfirstlane(d0.y);
            int t2 = __builtin_amdgcn_readfirstlane(d0.z);
            int t3 = __builtin_amdgcn_readfirstlane(d0.w);
            int t4 = __builtin_amdgcn_readfirstlane(d1.x);
            int t5 = __builtin_amdgcn_readfirstlane(d1.y);
            int t6 = __builtin_amdgcn_readfirstlane(d1.z);
            int t7 = __builtin_amdgcn_readfirstlane(d1.w);
            unsigned short u0 = hp[(long)t0 * 64 + lane], u1 = hp[(long)t1 * 64 + lane];
            unsigned short u2 = hp[(long)t2 * 64 + lane], u3 = hp[(long)t3 * 64 + lane];
            unsigned short u4 = hp[(long)t4 * 64 + lane], u5 = hp[(long)t5 * 64 + lane];
            unsigned short u6 = hp[(long)t6 * 64 + lane], u7 = hp[(long)t7 * 64 + lane];
            d0 = *(const int4*)(sl + j + 8);
            d1 = *(const int4*)(sl + j + 12);
            ACC8B();
            v0 = u0; v1 = u1; v2 = u2; v3 = u3; v4 = u4; v5 = u5; v6 = u6; v7 = u7;
        }
        ACC8B();
    }
    outp[(long)n * 64 + lane] = (a0 + a1 + a2 + a3) * dn + bias[lane];
}
#undef ACC8B

// ---------------- MEGA: P1|gemm1 -> CSR -> agg128 -> gemm2 -> agg64 ----------------
__global__ __launch_bounds__(256, 4) void mega_kernel(
    const int* __restrict__ src, const int* __restrict__ dst, int E, int p1Blocks,
    int gemmBlocks,
    unsigned* __restrict__ gcnt, unsigned* __restrict__ ebuf,
    const float* __restrict__ x, const bf16x8* __restrict__ wf1, __bf16* __restrict__ h1u,
    int* __restrict__ csr, int2* __restrict__ se, float* __restrict__ dinv,
    const float* __restrict__ b1, __bf16* __restrict__ agg1,
    const bf16x8* __restrict__ wf2, __bf16* __restrict__ h2s,
    const float* __restrict__ b2, float* __restrict__ outp,
    int N, unsigned* __restrict__ bar) {
    __shared__ unsigned sBuf[P1_EPB];  // 32 KB: sPacked (P1) / sEdges (CSR, first 4608)
    __shared__ int sCnt[256];
    __shared__ int sScan[256];
    int t = threadIdx.x;
    unsigned nblk = gridDim.x;

    // ---- phase 1: P1 bucket scatter | gemm1 (h1u = x @ W1, unscaled) ----
    int vb = (int)blockIdx.x;
    if (vb < p1Blocks) {
        sCnt[t] = 0;
        __syncthreads();
        long e0 = (long)vb * P1_EPB;
        int cnt = (int)(E - e0);
        if (cnt > P1_EPB) cnt = P1_EPB;
        for (int i = t; i < cnt; i += 256) {
            unsigned s = (unsigned)src[e0 + i];
            unsigned d = (unsigned)dst[e0 + i];
            sBuf[i] = (s << 16) | d;             // both < 2^16
            atomicAdd(&sCnt[d >> 8], 1);
        }
        __syncthreads();
        int base = 0;
        if (t < NBKT) base = (int)atomicAdd(&gcnt[t], (unsigned)sCnt[t]);
        __syncthreads();
        if (t < NBKT) sCnt[t] = t * EB_CAP + base;   // global cursor
        __syncthreads();
        for (int i = t; i < cnt; i += 256) {
            unsigned p = sBuf[i];
            int b = (int)((p & 0xffffu) >> 8);
            int pos = atomicAdd(&sCnt[b], 1);
            if (pos < (b + 1) * EB_CAP) ebuf[pos] = p;
        }
    } else if (vb < p1Blocks + gemmBlocks) {
        gemm_body<false, 256, 128, false>(vb - p1Blocks, t, x, wf1, nullptr, h1u, N);
    }
    grid_bar(bar, bar + 1, nblk);

    // ---- phase 2: per-bucket dense CSR (runs padded to x8 with sentinel N) ----
    if (blockIdx.x < NBKT) {
        int b = (int)blockIdx.x;
        int m = (int)gcnt[b];
        if (m > EB_CAP) m = EB_CAP;
        sCnt[t] = 0;
        __syncthreads();
        const unsigned* eb = ebuf + b * EB_CAP;
        for (int i = t; i < m; i += 256) {
            unsigned p = eb[i];
            sBuf[i] = p;
            atomicAdd(&sCnt[p & 255u], 1);
        }
        __syncthreads();
        int c = sCnt[t];
        int pad = (c + 7) & ~7;                 // pad run to multiple of 8
        sScan[t] = pad;
        __syncthreads();
        for (int off2 = 1; off2 < 256; off2 <<= 1) {
            int v = (t >= off2) ? sScan[t - off2] : 0;
            __syncthreads();
            sScan[t] += v;
            __syncthreads();
        }
        int start = b * CSR_CAP + sScan[t] - pad;   // exclusive scan; multiple of 8
        int node = (b << 8) + t;
        if (node < N) {
            se[node] = make_int2(start, start + pad);
            dinv[node] = rsqrtf((float)c + 1.0f);   // true degree (+1 self-loop)
        }
        __syncthreads();
        sCnt[t] = start;                         // reuse as cursor
        __syncthreads();
        for (int i = t; i < m; i += 256) {
            unsigned p = sBuf[i];
            int pos = atomicAdd(&sCnt[p & 255u], 1);
            csr[pos] = (int)(p >> 16);           // src
        }
        if (node < N) {
            for (int k = start + c; k < start + pad; k++) csr[k] = N;  // sentinel pad
        }
    }
    grid_bar(bar, bar + 1, nblk);

    // ---- phase 3: layer-1 aggregate (+bias, relu) ----
    {
        int gw = (int)blockIdx.x * 4 + (t >> 6), lane = t & 63;
        int stride = (int)nblk * 4;
        for (int n = gw; n < N; n += stride)
            agg128_node(n, lane, h1u, csr, se, dinv, b1, agg1);
    }
    grid_bar(bar, bar + 1, nblk);

    // ---- phase 4: h2s = (agg1 @ W2) * dinv[row] ----
    if ((int)blockIdx.x < gemmBlocks)
        gemm_body<true, 128, 64, true>((int)blockIdx.x, t, agg1, wf2, dinv, h2s, N);
    grid_bar(bar, bar + 1, nblk);

    // ---- phase 5: layer-2 aggregate -> d_out (fp32) ----
    {
        int gw = (int)blockIdx.x * 4 + (t >> 6), lane = t & 63;
        int stride = (int)nblk * 4;
        for (int n = gw; n < N; n += stride)
            agg64_node(n, lane, h2s, csr, se, dinv, b2, outp);
    }
}

static inline int cdiv(long a, long b) { return (int)((a + b - 1) / b); }

extern "C" void kernel_launch(void* const* d_in, const int* in_sizes, int n_in,
                              void* d_out, int out_size, void* d_ws, size_t ws_size,
                              hipStream_t stream) {
    const float* x  = (const float*)d_in[0];
    const int*   ei = (const int*)d_in[1];
    const float* W1 = (const float*)d_in[2];
    const float* b1 = (const float*)d_in[3];
    const float* W2 = (const float*)d_in[4];
    const float* b2 = (const float*)d_in[5];

    const int IN_C = 256;
    const int N = in_sizes[0] / IN_C;   // 50000
    const int E = in_sizes[1] / 2;      // 800000
    const int* src = ei;
    const int* dst = ei + E;

    char* w = (char*)d_ws;
    size_t off = 0;
    auto alloc = [&](size_t bytes) { void* p = w + off; off = (off + bytes + 255) & ~255ull; return p; };
    __bf16*   h1u  = (__bf16*)alloc((size_t)(N + 1) * 128 * 2); // +sentinel row
    __bf16*   agg1 = (__bf16*)alloc((size_t)N * 128 * 2);
    __bf16*   h2s  = (__bf16*)alloc((size_t)(N + 1) * 64 * 2);  // +sentinel row (zeroed)
    unsigned* ebuf = (unsigned*)alloc((size_t)NBKT * EB_CAP * 4);
    int*      csr  = (int*)alloc((size_t)NBKT * CSR_CAP * 4);
    int2*     se   = (int2*)alloc((size_t)N * 8);
    float*    dinv = (float*)alloc((size_t)(N + 1) * 4);        // +sentinel 0
    unsigned* gcnt = (unsigned*)alloc(NBKT * 4);
    unsigned* bar  = (unsigned*)alloc(256);                     // grid-barrier cnt/gen
    __bf16*   wf1  = (__bf16*)alloc(64 * 64 * 8 * 2);
    __bf16*   wf2  = (__bf16*)alloc(16 * 64 * 8 * 2);

    // K0: clear bucket counters + barrier + sentinel rows (block 0) + pack W frags
    int wprepBlocks = cdiv(64 * 64 + 16 * 64, TPB);  // 20
    clear_wprep_kernel<<<1 + wprepBlocks, TPB, 0, stream>>>(gcnt, dinv, h2s, N, bar,
                                                            W1, W2, wf1, wf2);

    // MEGA: everything else in one persistent kernel with grid barriers
    int p1Blocks = cdiv(E, P1_EPB);                  // 98
    int gemmBlocks = cdiv(N, 128);                   // 391
    mega_kernel<<<GRID_BLKS, TPB, 0, stream>>>(
        src, dst, E, p1Blocks, gemmBlocks, gcnt, ebuf, x, (const bf16x8*)wf1, h1u,
        csr, se, dinv, b1, agg1, (const bf16x8*)wf2, h2s, b2, (float*)d_out, N, bar);
}

// Round 3
// 193.278 us; speedup vs baseline: 5.9294x; 5.9294x over previous
//
#include <hip/hip_runtime.h>

// GCN 2-layer (R3). Two-level bucket CSR (LDS atomics only), sentinel-padded
// runs, bf16 MFMA GEMMs, pull aggregation. R2's grid-barrier mega-kernel is
// REVERTED (acquire-poll invalidate storm, 6x regression).
// R3 fusion: gemm2 folded into agg128 (row-wise, no cross-block dep): each
// wave aggregates 16 nodes -> stash relu rows bf16 in per-wave LDS (pad 132)
// -> 16 MFMA from LDS -> h2s directly. Removes K4 launch + agg1 round-trip.
// K0 clear+wprep -> K1 [P1-bucket | gemm1] -> K2 per-bucket CSR+dinv+pad ->
// K3 agg128+gemm2(*dinv) -> K5 agg64(+bias) -> d_out.

#define TPB 256
#define NBKT 196        // ceil(50000/256) buckets of 256 nodes
#define EB_CAP 4608     // edge-buffer slots per bucket (mean 4096 + 8 sigma)
#define CSR_CAP 6400    // 4608 + 256*7 pad-to-8 worst case
#define P1_EPB 8192     // edges per P1 block

typedef __bf16 bf16x8 __attribute__((ext_vector_type(8)));
typedef __bf16 bf16x4 __attribute__((ext_vector_type(4)));
typedef __bf16 bf16x2 __attribute__((ext_vector_type(2)));
typedef float f32x4 __attribute__((ext_vector_type(4)));

__device__ __forceinline__ float bflo(unsigned u) { return __uint_as_float(u << 16); }
__device__ __forceinline__ float bfhi(unsigned u) { return __uint_as_float(u & 0xffff0000u); }

// ---------------- K0: clear gcnt, zero sentinel rows, W frag pack ----------------
// A-frag (16x16x32): lane L holds A[m=L&15][k=(L>>4)*8+j]; A[m][k]=W[k][oct*16+m].
__global__ __launch_bounds__(256) void clear_wprep_kernel(
    unsigned* __restrict__ gcnt, float* __restrict__ dinv, __bf16* __restrict__ h2s,
    int N,
    const float* __restrict__ W1, const float* __restrict__ W2,
    __bf16* __restrict__ wf1, __bf16* __restrict__ wf2) {
    if (blockIdx.x == 0) {
        int t = threadIdx.x;
        if (t < NBKT) gcnt[t] = 0;
        if (t == 0) dinv[N] = 0.0f;                       // sentinel weight
        if (t < 32) ((unsigned*)(h2s + (long)N * 64))[t] = 0u;  // sentinel row = 0
        return;
    }
    int g = (blockIdx.x - 1) * TPB + threadIdx.x;
    if (g < 64 * 64) {  // W1: K=256 (8 ksteps), OC=128 (8 octiles)
        int frag = g >> 6, L = g & 63;
        int kstep = frag >> 3, oct = frag & 7;
        int oc = oct * 16 + (L & 15);
        int k0 = kstep * 32 + (L >> 4) * 8;
        bf16x8 v;
#pragma unroll
        for (int j = 0; j < 8; j++) v[j] = (__bf16)W1[(k0 + j) * 128 + oc];
        ((bf16x8*)wf1)[g] = v;
    } else if (g < 64 * 64 + 16 * 64) {  // W2: K=128 (4), OC=64 (4)
        int g2 = g - 64 * 64;
        int frag = g2 >> 6, L = g2 & 63;
        int kstep = frag >> 2, oct = frag & 3;
        int oc = oct * 16 + (L & 15);
        int k0 = kstep * 32 + (L >> 4) * 8;
        bf16x8 v;
#pragma unroll
        for (int j = 0; j < 8; j++) v[j] = (__bf16)W2[(k0 + j) * 64 + oc];
        ((bf16x8*)wf2)[g2] = v;
    }
}

// ---------------- MFMA GEMM body (used by gemm1) ----------------
// out[r][oc] = (sum_k A[r][k]*W[k][oc]) * (SCALE ? dinv[r] : 1), bf16 out. Wave: 32 rows.
template <bool IN_BF16, int K, int OC, bool SCALE>
__device__ __forceinline__ void gemm_body(int bid, int tid, const void* __restrict__ Ain,
                                          const bf16x8* __restrict__ wfrag,
                                          const float* __restrict__ dinv,
                                          __bf16* __restrict__ outp, int M) {
    constexpr int KS = K / 32, OT = OC / 16;
    int wave = tid >> 6, lane = tid & 63;
    int col = lane & 15, q = lane >> 4;
    long rb = (long)bid * 128 + wave * 32;
    long r0 = rb + col, r1 = rb + 16 + col;
    long r0c = (r0 < M) ? r0 : (M - 1);
    long r1c = (r1 < M) ? r1 : (M - 1);

    f32x4 acc[OT][2];
#pragma unroll
    for (int o = 0; o < OT; o++) {
        acc[o][0] = (f32x4){0.f, 0.f, 0.f, 0.f};
        acc[o][1] = (f32x4){0.f, 0.f, 0.f, 0.f};
    }

#pragma unroll
    for (int ks = 0; ks < KS; ks++) {
        int k0 = ks * 32 + q * 8;
        bf16x8 b0, b1;
        if constexpr (IN_BF16) {
            const __bf16* A = (const __bf16*)Ain;
            b0 = *(const bf16x8*)(A + r0c * K + k0);
            b1 = *(const bf16x8*)(A + r1c * K + k0);
        } else {
            const float* A = (const float*)Ain;
            float4 f0a = *(const float4*)(A + r0c * K + k0);
            float4 f0b = *(const float4*)(A + r0c * K + k0 + 4);
            float4 f1a = *(const float4*)(A + r1c * K + k0);
            float4 f1b = *(const float4*)(A + r1c * K + k0 + 4);
            b0[0] = (__bf16)f0a.x; b0[1] = (__bf16)f0a.y; b0[2] = (__bf16)f0a.z; b0[3] = (__bf16)f0a.w;
            b0[4] = (__bf16)f0b.x; b0[5] = (__bf16)f0b.y; b0[6] = (__bf16)f0b.z; b0[7] = (__bf16)f0b.w;
            b1[0] = (__bf16)f1a.x; b1[1] = (__bf16)f1a.y; b1[2] = (__bf16)f1a.z; b1[3] = (__bf16)f1a.w;
            b1[4] = (__bf16)f1b.x; b1[5] = (__bf16)f1b.y; b1[6] = (__bf16)f1b.z; b1[7] = (__bf16)f1b.w;
        }
#pragma unroll
        for (int ot = 0; ot < OT; ot++) {
            bf16x8 a = wfrag[(ks * OT + ot) * 64 + lane];
            acc[ot][0] = __builtin_amdgcn_mfma_f32_16x16x32_bf16(a, b0, acc[ot][0], 0, 0, 0);
            acc[ot][1] = __builtin_amdgcn_mfma_f32_16x16x32_bf16(a, b1, acc[ot][1], 0, 0, 0);
        }
    }

    float sc0 = 1.f, sc1 = 1.f;
    if constexpr (SCALE) {
        sc0 = dinv[r0c];
        sc1 = dinv[r1c];
    }
#pragma unroll
    for (int ot = 0; ot < OT; ot++) {
        int oc = ot * 16 + q * 4;
        if (r0 < M) {
            bf16x4 v;
#pragma unroll
            for (int r = 0; r < 4; r++) v[r] = (__bf16)(acc[ot][0][r] * sc0);
            *(bf16x4*)(outp + r0 * OC + oc) = v;
        }
        if (r1 < M) {
            bf16x4 v;
#pragma unroll
            for (int r = 0; r < 4; r++) v[r] = (__bf16)(acc[ot][1][r] * sc1);
            *(bf16x4*)(outp + r1 * OC + oc) = v;
        }
    }
}

// ---------------- K1: P1 bucket scatter (LDS) | gemm1 (unscaled) ----------------
__global__ __launch_bounds__(256) void p1_gemm1_kernel(
    const int* __restrict__ src, const int* __restrict__ dst, int E, int p1Blocks,
    unsigned* __restrict__ gcnt, unsigned* __restrict__ ebuf,
    const float* __restrict__ x, const bf16x8* __restrict__ wf1,
    __bf16* __restrict__ h1u, int M) {
    __shared__ unsigned sPacked[P1_EPB];  // 32 KB
    __shared__ int sCnt[256];
    if ((int)blockIdx.x < p1Blocks) {
        int t = threadIdx.x;
        sCnt[t] = 0;
        __syncthreads();
        long e0 = (long)blockIdx.x * P1_EPB;
        int cnt = (int)(E - e0);
        if (cnt > P1_EPB) cnt = P1_EPB;
        for (int i = t; i < cnt; i += 256) {
            unsigned s = (unsigned)src[e0 + i];
            unsigned d = (unsigned)dst[e0 + i];
            sPacked[i] = (s << 16) | d;          // both < 2^16
            atomicAdd(&sCnt[d >> 8], 1);
        }
        __syncthreads();
        int base = 0;
        if (t < NBKT) base = (int)atomicAdd(&gcnt[t], (unsigned)sCnt[t]);
        __syncthreads();
        if (t < NBKT) sCnt[t] = t * EB_CAP + base;   // global cursor
        __syncthreads();
        for (int i = t; i < cnt; i += 256) {
            unsigned p = sPacked[i];
            int b = (int)((p & 0xffffu) >> 8);
            int pos = atomicAdd(&sCnt[b], 1);
            if (pos < (b + 1) * EB_CAP) ebuf[pos] = p;
        }
    } else {
        gemm_body<false, 256, 128, false>(blockIdx.x - p1Blocks, threadIdx.x,
                                          x, wf1, nullptr, h1u, M);
    }
}

// ---------------- K2: per-bucket dense CSR (runs padded to x8 with sentinel N) ----------------
__global__ __launch_bounds__(256) void csr_kernel(
    const unsigned* __restrict__ gcnt, const unsigned* __restrict__ ebuf,
    int* __restrict__ csr, int2* __restrict__ se, float* __restrict__ dinv, int N) {
    __shared__ unsigned sEdges[EB_CAP];  // 18 KB
    __shared__ int sCnt[256];
    __shared__ int sScan[256];
    int b = blockIdx.x, t = threadIdx.x;
    int m = (int)gcnt[b];
    if (m > EB_CAP) m = EB_CAP;
    sCnt[t] = 0;
    __syncthreads();
    const unsigned* eb = ebuf + b * EB_CAP;
    for (int i = t; i < m; i += 256) {
        unsigned p = eb[i];
        sEdges[i] = p;
        atomicAdd(&sCnt[p & 255u], 1);
    }
    __syncthreads();
    int c = sCnt[t];
    int pad = (c + 7) & ~7;                 // pad run to multiple of 8
    sScan[t] = pad;
    __syncthreads();
    for (int off = 1; off < 256; off <<= 1) {
        int v = (t >= off) ? sScan[t - off] : 0;
        __syncthreads();
        sScan[t] += v;
        __syncthreads();
    }
    int start = b * CSR_CAP + sScan[t] - pad;   // exclusive scan; multiple of 8
    int node = (b << 8) + t;
    if (node < N) {
        se[node] = make_int2(start, start + pad);  // loop extent = padded
        dinv[node] = rsqrtf((float)c + 1.0f);      // true degree (+1 self-loop)
    }
    __syncthreads();
    sCnt[t] = start;                         // reuse as cursor
    __syncthreads();
    for (int i = t; i < m; i += 256) {
        unsigned p = sEdges[i];
        int pos = atomicAdd(&sCnt[p & 255u], 1);
        csr[pos] = (int)(p >> 16);           // src
    }
    // sentinel-fill pad slots (dinv[N]=0 -> zero contribution)
    if (node < N) {
        for (int k = start + c; k < start + pad; k++) csr[k] = N;
    }
}

// ---------------- K3: agg128 (pipelined, scalarized) + fused gemm2 ----------------
// Each wave: 16 consecutive nodes. Per node: pull-aggregate (R1 core), +bias,
// relu -> stash bf16 row in per-wave LDS tile (pad stride 132 bf16). After 16
// nodes: B-frags from LDS, 16 MFMA vs wf2, scale dinv[row], store h2s.
#define ACC8()                                             \
    do {                                                   \
        a0x += bflo(v0) * w0; a0y += bfhi(v0) * w0;        \
        a1x += bflo(v1) * w1; a1y += bfhi(v1) * w1;        \
        a2x += bflo(v2) * w2; a2y += bfhi(v2) * w2;        \
        a3x += bflo(v3) * w3; a3y += bfhi(v3) * w3;        \
        a0x += bflo(v4) * w4; a0y += bfhi(v4) * w4;        \
        a1x += bflo(v5) * w5; a1y += bfhi(v5) * w5;        \
        a2x += bflo(v6) * w6; a2y += bfhi(v6) * w6;        \
        a3x += bflo(v7) * w7; a3y += bfhi(v7) * w7;        \
    } while (0)

__global__ __launch_bounds__(256) void agg128_gemm2_kernel(
    const __bf16* __restrict__ h, const int* __restrict__ csr,
    const int2* __restrict__ se, const float* __restrict__ dinv,
    const float* __restrict__ bias, const bf16x8* __restrict__ wf2,
    __bf16* __restrict__ h2s, int N) {
    __shared__ __bf16 stash[4][16 * 132];  // per-wave 16 rows x 132(pad) bf16 = 16.5KB
    int wave = threadIdx.x >> 6, lane = threadIdx.x & 63;
    int n0 = blockIdx.x * 64 + wave * 16;  // this wave's 16 nodes
    unsigned* stw = (unsigned*)stash[wave];  // dword view, row stride 66 words

    for (int i = 0; i < 16; i++) {
        int n = n0 + i;
        float ox = 0.f, oy = 0.f;
        if (n < N) {
            int2 s_e = se[n];
            int start = s_e.x, m = s_e.y - s_e.x;    // m % 8 == 0
            float dn = dinv[n];
            const unsigned* hp = (const unsigned*)h;  // 2 bf16/word, stride 64 words
            const int* sl = csr + start;              // 32B-aligned
            unsigned self = hp[(long)n * 64 + lane];
            float a0x = bflo(self) * dn, a0y = bfhi(self) * dn;  // *dn at end -> dinv^2
            float a1x = 0.f, a1y = 0.f, a2x = 0.f, a2y = 0.f, a3x = 0.f, a3y = 0.f;
            if (m > 0) {
                int4 c0 = *(const int4*)sl;
                int4 c1 = *(const int4*)(sl + 4);
                int i0 = __builtin_amdgcn_readfirstlane(c0.x);
                int i1 = __builtin_amdgcn_readfirstlane(c0.y);
                int i2 = __builtin_amdgcn_readfirstlane(c0.z);
                int i3 = __builtin_amdgcn_readfirstlane(c0.w);
                int i4 = __builtin_amdgcn_readfirstlane(c1.x);
                int i5 = __builtin_amdgcn_readfirstlane(c1.y);
                int i6 = __builtin_amdgcn_readfirstlane(c1.z);
                int i7 = __builtin_amdgcn_readfirstlane(c1.w);
                unsigned v0 = hp[(long)i0 * 64 + lane], v1 = hp[(long)i1 * 64 + lane];
                unsigned v2 = hp[(long)i2 * 64 + lane], v3 = hp[(long)i3 * 64 + lane];
                unsigned v4 = hp[(long)i4 * 64 + lane], v5 = hp[(long)i5 * 64 + lane];
                unsigned v6 = hp[(long)i6 * 64 + lane], v7 = hp[(long)i7 * 64 + lane];
                float w0 = dinv[i0], w1 = dinv[i1], w2 = dinv[i2], w3 = dinv[i3];
                float w4 = dinv[i4], w5 = dinv[i5], w6 = dinv[i6], w7 = dinv[i7];
                int4 d0 = *(const int4*)(sl + 8);   // safe over-read (se follows csr)
                int4 d1 = *(const int4*)(sl + 12);
                for (int j = 8; j < m; j += 8) {
                    int t0 = __builtin_amdgcn_readfirstlane(d0.x);
                    int t1 = __builtin_amdgcn_readfirstlane(d0.y);
                    int t2 = __builtin_amdgcn_readfirstlane(d0.z);
                    int t3 = __builtin_amdgcn_readfirstlane(d0.w);
                    int t4 = __builtin_amdgcn_readfirstlane(d1.x);
                    int t5 = __builtin_amdgcn_readfirstlane(d1.y);
                    int t6 = __builtin_amdgcn_readfirstlane(d1.z);
                    int t7 = __builtin_amdgcn_readfirstlane(d1.w);
                    unsigned u0 = hp[(long)t0 * 64 + lane], u1 = hp[(long)t1 * 64 + lane];
                    unsigned u2 = hp[(long)t2 * 64 + lane], u3 = hp[(long)t3 * 64 + lane];
                    unsigned u4 = hp[(long)t4 * 64 + lane], u5 = hp[(long)t5 * 64 + lane];
                    unsigned u6 = hp[(long)t6 * 64 + lane], u7 = hp[(long)t7 * 64 + lane];
                    float q0 = dinv[t0], q1 = dinv[t1], q2 = dinv[t2], q3 = dinv[t3];
                    float q4 = dinv[t4], q5 = dinv[t5], q6 = dinv[t6], q7 = dinv[t7];
                    d0 = *(const int4*)(sl + j + 8);
                    d1 = *(const int4*)(sl + j + 12);
                    ACC8();
                    v0 = u0; v1 = u1; v2 = u2; v3 = u3; v4 = u4; v5 = u5; v6 = u6; v7 = u7;
                    w0 = q0; w1 = q1; w2 = q2; w3 = q3; w4 = q4; w5 = q5; w6 = q6; w7 = q7;
                }
                ACC8();
            }
            float2 bv = ((const float2*)bias)[lane];
            ox = fmaxf((a0x + a1x + a2x + a3x) * dn + bv.x, 0.f);
            oy = fmaxf((a0y + a1y + a2y + a3y) * dn + bv.y, 0.f);
        }
        bf16x2 st = {(__bf16)ox, (__bf16)oy};  // invalid nodes stash zeros
        stw[i * 66 + lane] = *(unsigned*)&st;  // bank = (2i+lane)%32, conflict-free
    }

    // gemm2 from LDS: rows = 16 stashed nodes (B), cols = 64 OC (A=wf2), K=128
    int col = lane & 15, q = lane >> 4;
    const __bf16* srow = stash[wave] + col * 132;
    f32x4 acc[4];
#pragma unroll
    for (int ot = 0; ot < 4; ot++) acc[ot] = (f32x4){0.f, 0.f, 0.f, 0.f};
#pragma unroll
    for (int ks = 0; ks < 4; ks++) {
        bf16x8 bb = *(const bf16x8*)(srow + ks * 32 + q * 8);
#pragma unroll
        for (int ot = 0; ot < 4; ot++) {
            bf16x8 a = wf2[(ks * 4 + ot) * 64 + lane];
            acc[ot] = __builtin_amdgcn_mfma_f32_16x16x32_bf16(a, bb, acc[ot], 0, 0, 0);
        }
    }
    int node = n0 + col;
    bool valid = node < N;
    float dn2 = valid ? dinv[node] : 0.f;
#pragma unroll
    for (int ot = 0; ot < 4; ot++) {
        int oc = ot * 16 + q * 4;
        if (valid) {
            bf16x4 v;
#pragma unroll
            for (int r = 0; r < 4; r++) v[r] = (__bf16)(acc[ot][r] * dn2);
            *(bf16x4*)(h2s + (long)node * 64 + oc) = v;
        }
    }
}
#undef ACC8

// ---------------- K5: agg64 (h2s pre-scaled by dinv[row]; sentinel row = 0) ----------------
// self term: h2s[n] already carries dinv[n]; final *dn gives dinv^2 (no extra *dn).
#define ACC8B()                                                                            \
    do {                                                                                   \
        a0 += __uint_as_float((unsigned)v0 << 16); a1 += __uint_as_float((unsigned)v1 << 16); \
        a2 += __uint_as_float((unsigned)v2 << 16); a3 += __uint_as_float((unsigned)v3 << 16); \
        a0 += __uint_as_float((unsigned)v4 << 16); a1 += __uint_as_float((unsigned)v5 << 16); \
        a2 += __uint_as_float((unsigned)v6 << 16); a3 += __uint_as_float((unsigned)v7 << 16); \
    } while (0)

__global__ __launch_bounds__(256) void agg64_kernel(const __bf16* __restrict__ hs,
                                                    const int* __restrict__ csr,
                                                    const int2* __restrict__ se,
                                                    const float* __restrict__ dinv,
                                                    const float* __restrict__ bias,
                                                    float* __restrict__ outp, int N) {
    int gid = blockIdx.x * TPB + threadIdx.x;
    int n = gid >> 6, lane = gid & 63;
    if (n >= N) return;
    int2 s_e = se[n];
    int start = s_e.x, m = s_e.y - s_e.x;    // m % 8 == 0
    float dn = dinv[n];
    const unsigned short* hp = (const unsigned short*)hs;  // row stride 64
    const int* sl = csr + start;
    float a0 = __uint_as_float(((unsigned)hp[(long)n * 64 + lane]) << 16);
    float a1 = 0.f, a2 = 0.f, a3 = 0.f;
    if (m > 0) {
        int4 c0 = *(const int4*)sl;
        int4 c1 = *(const int4*)(sl + 4);
        int i0 = __builtin_amdgcn_readfirstlane(c0.x);
        int i1 = __builtin_amdgcn_readfirstlane(c0.y);
        int i2 = __builtin_amdgcn_readfirstlane(c0.z);
        int i3 = __builtin_amdgcn_readfirstlane(c0.w);
        int i4 = __builtin_amdgcn_readfirstlane(c1.x);
        int i5 = __builtin_amdgcn_readfirstlane(c1.y);
        int i6 = __builtin_amdgcn_readfirstlane(c1.z);
        int i7 = __builtin_amdgcn_readfirstlane(c1.w);
        unsigned short v0 = hp[(long)i0 * 64 + lane], v1 = hp[(long)i1 * 64 + lane];
        unsigned short v2 = hp[(long)i2 * 64 + lane], v3 = hp[(long)i3 * 64 + lane];
        unsigned short v4 = hp[(long)i4 * 64 + lane], v5 = hp[(long)i5 * 64 + lane];
        unsigned short v6 = hp[(long)i6 * 64 + lane], v7 = hp[(long)i7 * 64 + lane];
        int4 d0 = *(const int4*)(sl + 8);
        int4 d1 = *(const int4*)(sl + 12);
        for (int j = 8; j < m; j += 8) {
            int t0 = __builtin_amdgcn_readfirstlane(d0.x);
            int t1 = __builtin_amdgcn_readfirstlane(d0.y);
            int t2 = __builtin_amdgcn_readfirstlane(d0.z);
            int t3 = __builtin_amdgcn_readfirstlane(d0.w);
            int t4 = __builtin_amdgcn_readfirstlane(d1.x);
            int t5 = __builtin_amdgcn_readfirstlane(d1.y);
            int t6 = __builtin_amdgcn_readfirstlane(d1.z);
            int t7 = __builtin_amdgcn_readfirstlane(d1.w);
            unsigned short u0 = hp[(long)t0 * 64 + lane], u1 = hp[(long)t1 * 64 + lane];
            unsigned short u2 = hp[(long)t2 * 64 + lane], u3 = hp[(long)t3 * 64 + lane];
            unsigned short u4 = hp[(long)t4 * 64 + lane], u5 = hp[(long)t5 * 64 + lane];
            unsigned short u6 = hp[(long)t6 * 64 + lane], u7 = hp[(long)t7 * 64 + lane];
            d0 = *(const int4*)(sl + j + 8);
            d1 = *(const int4*)(sl + j + 12);
            ACC8B();
            v0 = u0; v1 = u1; v2 = u2; v3 = u3; v4 = u4; v5 = u5; v6 = u6; v7 = u7;
        }
        ACC8B();
    }
    outp[(long)n * 64 + lane] = (a0 + a1 + a2 + a3) * dn + bias[lane];
}
#undef ACC8B

static inline int cdiv(long a, long b) { return (int)((a + b - 1) / b); }

extern "C" void kernel_launch(void* const* d_in, const int* in_sizes, int n_in,
                              void* d_out, int out_size, void* d_ws, size_t ws_size,
                              hipStream_t stream) {
    const float* x  = (const float*)d_in[0];
    const int*   ei = (const int*)d_in[1];
    const float* W1 = (const float*)d_in[2];
    const float* b1 = (const float*)d_in[3];
    const float* W2 = (const float*)d_in[4];
    const float* b2 = (const float*)d_in[5];

    const int IN_C = 256;
    const int N = in_sizes[0] / IN_C;   // 50000
    const int E = in_sizes[1] / 2;      // 800000
    const int* src = ei;
    const int* dst = ei + E;

    char* w = (char*)d_ws;
    size_t off = 0;
    auto alloc = [&](size_t bytes) { void* p = w + off; off = (off + bytes + 255) & ~255ull; return p; };
    __bf16*   h1u  = (__bf16*)alloc((size_t)(N + 1) * 128 * 2); // +sentinel row
    __bf16*   h2s  = (__bf16*)alloc((size_t)(N + 1) * 64 * 2);  // +sentinel row (zeroed)
    unsigned* ebuf = (unsigned*)alloc((size_t)NBKT * EB_CAP * 4);
    int*      csr  = (int*)alloc((size_t)NBKT * CSR_CAP * 4);
    int2*     se   = (int2*)alloc((size_t)N * 8);
    float*    dinv = (float*)alloc((size_t)(N + 1) * 4);        // +sentinel 0
    unsigned* gcnt = (unsigned*)alloc(NBKT * 4);
    __bf16*   wf1  = (__bf16*)alloc(64 * 64 * 8 * 2);
    __bf16*   wf2  = (__bf16*)alloc(16 * 64 * 8 * 2);

    // K0: clear bucket counters + sentinel rows (block 0) + pack W frags
    int wprepBlocks = cdiv(64 * 64 + 16 * 64, TPB);  // 20
    clear_wprep_kernel<<<1 + wprepBlocks, TPB, 0, stream>>>(gcnt, dinv, h2s, N,
                                                            W1, W2, wf1, wf2);

    // K1: bucket scatter (LDS two-pass) | gemm1 (h1u = x @ W1, unscaled)
    int p1Blocks = cdiv(E, P1_EPB);                  // 98
    int gemmBlocks = cdiv(N, 128);                   // 391
    p1_gemm1_kernel<<<p1Blocks + gemmBlocks, TPB, 0, stream>>>(
        src, dst, E, p1Blocks, gcnt, ebuf, x, (const bf16x8*)wf1, h1u, N);

    // K2: per-bucket dense CSR + dinv + (start, start+pad), sentinel-padded
    csr_kernel<<<NBKT, TPB, 0, stream>>>(gcnt, ebuf, csr, se, dinv, N);

    // K3: layer-1 aggregate (+bias, relu) fused with gemm2 -> h2s
    agg128_gemm2_kernel<<<cdiv(N, 64), TPB, 0, stream>>>(h1u, csr, se, dinv, b1,
                                                         (const bf16x8*)wf2, h2s, N);

    // K5: layer-2 aggregate -> d_out (fp32)
    agg64_kernel<<<cdiv((long)N * 64, TPB), TPB, 0, stream>>>(h2s, csr, se, dinv, b2,
                                                              (float*)d_out, N);
}

// Round 4
// 179.217 us; speedup vs baseline: 6.3946x; 1.0785x over previous
//
#include <hip/hip_runtime.h>

// GCN 2-layer (R4). Two-level bucket CSR (LDS atomics only), sentinel-padded
// runs, bf16 MFMA GEMMs, pull aggregation.
// R4: fused agg128+gemm2 re-decomposed for occupancy: block = 16 nodes,
// wave = 4 nodes (R3's 16-nodes-per-wave starved TLP: 782 blocks -> 25% occ).
// Grid cdiv(N,16)=3125 blocks -> full 32 waves/CU. Block-shared 16x132 stash,
// one syncthreads, gemm2 split by octile across the 4 waves (4 MFMA/wave).
// K0 clear+wprep -> K1 [P1-bucket | gemm1] -> K2 per-bucket CSR+dinv+pad ->
// K3 agg128+gemm2(*dinv) -> K5 agg64(+bias) -> d_out.

#define TPB 256
#define NBKT 196        // ceil(50000/256) buckets of 256 nodes
#define EB_CAP 4608     // edge-buffer slots per bucket (mean 4096 + 8 sigma)
#define CSR_CAP 6400    // 4608 + 256*7 pad-to-8 worst case
#define P1_EPB 8192     // edges per P1 block

typedef __bf16 bf16x8 __attribute__((ext_vector_type(8)));
typedef __bf16 bf16x4 __attribute__((ext_vector_type(4)));
typedef __bf16 bf16x2 __attribute__((ext_vector_type(2)));
typedef float f32x4 __attribute__((ext_vector_type(4)));

__device__ __forceinline__ float bflo(unsigned u) { return __uint_as_float(u << 16); }
__device__ __forceinline__ float bfhi(unsigned u) { return __uint_as_float(u & 0xffff0000u); }

// ---------------- K0: clear gcnt, zero sentinel rows, W frag pack ----------------
// A-frag (16x16x32): lane L holds A[m=L&15][k=(L>>4)*8+j]; A[m][k]=W[k][oct*16+m].
__global__ __launch_bounds__(256) void clear_wprep_kernel(
    unsigned* __restrict__ gcnt, float* __restrict__ dinv, __bf16* __restrict__ h2s,
    int N,
    const float* __restrict__ W1, const float* __restrict__ W2,
    __bf16* __restrict__ wf1, __bf16* __restrict__ wf2) {
    if (blockIdx.x == 0) {
        int t = threadIdx.x;
        if (t < NBKT) gcnt[t] = 0;
        if (t == 0) dinv[N] = 0.0f;                       // sentinel weight
        if (t < 32) ((unsigned*)(h2s + (long)N * 64))[t] = 0u;  // sentinel row = 0
        return;
    }
    int g = (blockIdx.x - 1) * TPB + threadIdx.x;
    if (g < 64 * 64) {  // W1: K=256 (8 ksteps), OC=128 (8 octiles)
        int frag = g >> 6, L = g & 63;
        int kstep = frag >> 3, oct = frag & 7;
        int oc = oct * 16 + (L & 15);
        int k0 = kstep * 32 + (L >> 4) * 8;
        bf16x8 v;
#pragma unroll
        for (int j = 0; j < 8; j++) v[j] = (__bf16)W1[(k0 + j) * 128 + oc];
        ((bf16x8*)wf1)[g] = v;
    } else if (g < 64 * 64 + 16 * 64) {  // W2: K=128 (4), OC=64 (4)
        int g2 = g - 64 * 64;
        int frag = g2 >> 6, L = g2 & 63;
        int kstep = frag >> 2, oct = frag & 3;
        int oc = oct * 16 + (L & 15);
        int k0 = kstep * 32 + (L >> 4) * 8;
        bf16x8 v;
#pragma unroll
        for (int j = 0; j < 8; j++) v[j] = (__bf16)W2[(k0 + j) * 64 + oc];
        ((bf16x8*)wf2)[g2] = v;
    }
}

// ---------------- MFMA GEMM body (used by gemm1) ----------------
// out[r][oc] = (sum_k A[r][k]*W[k][oc]) * (SCALE ? dinv[r] : 1), bf16 out. Wave: 32 rows.
template <bool IN_BF16, int K, int OC, bool SCALE>
__device__ __forceinline__ void gemm_body(int bid, int tid, const void* __restrict__ Ain,
                                          const bf16x8* __restrict__ wfrag,
                                          const float* __restrict__ dinv,
                                          __bf16* __restrict__ outp, int M) {
    constexpr int KS = K / 32, OT = OC / 16;
    int wave = tid >> 6, lane = tid & 63;
    int col = lane & 15, q = lane >> 4;
    long rb = (long)bid * 128 + wave * 32;
    long r0 = rb + col, r1 = rb + 16 + col;
    long r0c = (r0 < M) ? r0 : (M - 1);
    long r1c = (r1 < M) ? r1 : (M - 1);

    f32x4 acc[OT][2];
#pragma unroll
    for (int o = 0; o < OT; o++) {
        acc[o][0] = (f32x4){0.f, 0.f, 0.f, 0.f};
        acc[o][1] = (f32x4){0.f, 0.f, 0.f, 0.f};
    }

#pragma unroll
    for (int ks = 0; ks < KS; ks++) {
        int k0 = ks * 32 + q * 8;
        bf16x8 b0, b1;
        if constexpr (IN_BF16) {
            const __bf16* A = (const __bf16*)Ain;
            b0 = *(const bf16x8*)(A + r0c * K + k0);
            b1 = *(const bf16x8*)(A + r1c * K + k0);
        } else {
            const float* A = (const float*)Ain;
            float4 f0a = *(const float4*)(A + r0c * K + k0);
            float4 f0b = *(const float4*)(A + r0c * K + k0 + 4);
            float4 f1a = *(const float4*)(A + r1c * K + k0);
            float4 f1b = *(const float4*)(A + r1c * K + k0 + 4);
            b0[0] = (__bf16)f0a.x; b0[1] = (__bf16)f0a.y; b0[2] = (__bf16)f0a.z; b0[3] = (__bf16)f0a.w;
            b0[4] = (__bf16)f0b.x; b0[5] = (__bf16)f0b.y; b0[6] = (__bf16)f0b.z; b0[7] = (__bf16)f0b.w;
            b1[0] = (__bf16)f1a.x; b1[1] = (__bf16)f1a.y; b1[2] = (__bf16)f1a.z; b1[3] = (__bf16)f1a.w;
            b1[4] = (__bf16)f1b.x; b1[5] = (__bf16)f1b.y; b1[6] = (__bf16)f1b.z; b1[7] = (__bf16)f1b.w;
        }
#pragma unroll
        for (int ot = 0; ot < OT; ot++) {
            bf16x8 a = wfrag[(ks * OT + ot) * 64 + lane];
            acc[ot][0] = __builtin_amdgcn_mfma_f32_16x16x32_bf16(a, b0, acc[ot][0], 0, 0, 0);
            acc[ot][1] = __builtin_amdgcn_mfma_f32_16x16x32_bf16(a, b1, acc[ot][1], 0, 0, 0);
        }
    }

    float sc0 = 1.f, sc1 = 1.f;
    if constexpr (SCALE) {
        sc0 = dinv[r0c];
        sc1 = dinv[r1c];
    }
#pragma unroll
    for (int ot = 0; ot < OT; ot++) {
        int oc = ot * 16 + q * 4;
        if (r0 < M) {
            bf16x4 v;
#pragma unroll
            for (int r = 0; r < 4; r++) v[r] = (__bf16)(acc[ot][0][r] * sc0);
            *(bf16x4*)(outp + r0 * OC + oc) = v;
        }
        if (r1 < M) {
            bf16x4 v;
#pragma unroll
            for (int r = 0; r < 4; r++) v[r] = (__bf16)(acc[ot][1][r] * sc1);
            *(bf16x4*)(outp + r1 * OC + oc) = v;
        }
    }
}

// ---------------- K1: P1 bucket scatter (LDS) | gemm1 (unscaled) ----------------
__global__ __launch_bounds__(256) void p1_gemm1_kernel(
    const int* __restrict__ src, const int* __restrict__ dst, int E, int p1Blocks,
    unsigned* __restrict__ gcnt, unsigned* __restrict__ ebuf,
    const float* __restrict__ x, const bf16x8* __restrict__ wf1,
    __bf16* __restrict__ h1u, int M) {
    __shared__ unsigned sPacked[P1_EPB];  // 32 KB
    __shared__ int sCnt[256];
    if ((int)blockIdx.x < p1Blocks) {
        int t = threadIdx.x;
        sCnt[t] = 0;
        __syncthreads();
        long e0 = (long)blockIdx.x * P1_EPB;
        int cnt = (int)(E - e0);
        if (cnt > P1_EPB) cnt = P1_EPB;
        for (int i = t; i < cnt; i += 256) {
            unsigned s = (unsigned)src[e0 + i];
            unsigned d = (unsigned)dst[e0 + i];
            sPacked[i] = (s << 16) | d;          // both < 2^16
            atomicAdd(&sCnt[d >> 8], 1);
        }
        __syncthreads();
        int base = 0;
        if (t < NBKT) base = (int)atomicAdd(&gcnt[t], (unsigned)sCnt[t]);
        __syncthreads();
        if (t < NBKT) sCnt[t] = t * EB_CAP + base;   // global cursor
        __syncthreads();
        for (int i = t; i < cnt; i += 256) {
            unsigned p = sPacked[i];
            int b = (int)((p & 0xffffu) >> 8);
            int pos = atomicAdd(&sCnt[b], 1);
            if (pos < (b + 1) * EB_CAP) ebuf[pos] = p;
        }
    } else {
        gemm_body<false, 256, 128, false>(blockIdx.x - p1Blocks, threadIdx.x,
                                          x, wf1, nullptr, h1u, M);
    }
}

// ---------------- K2: per-bucket dense CSR (runs padded to x8 with sentinel N) ----------------
__global__ __launch_bounds__(256) void csr_kernel(
    const unsigned* __restrict__ gcnt, const unsigned* __restrict__ ebuf,
    int* __restrict__ csr, int2* __restrict__ se, float* __restrict__ dinv, int N) {
    __shared__ unsigned sEdges[EB_CAP];  // 18 KB
    __shared__ int sCnt[256];
    __shared__ int sScan[256];
    int b = blockIdx.x, t = threadIdx.x;
    int m = (int)gcnt[b];
    if (m > EB_CAP) m = EB_CAP;
    sCnt[t] = 0;
    __syncthreads();
    const unsigned* eb = ebuf + b * EB_CAP;
    for (int i = t; i < m; i += 256) {
        unsigned p = eb[i];
        sEdges[i] = p;
        atomicAdd(&sCnt[p & 255u], 1);
    }
    __syncthreads();
    int c = sCnt[t];
    int pad = (c + 7) & ~7;                 // pad run to multiple of 8
    sScan[t] = pad;
    __syncthreads();
    for (int off = 1; off < 256; off <<= 1) {
        int v = (t >= off) ? sScan[t - off] : 0;
        __syncthreads();
        sScan[t] += v;
        __syncthreads();
    }
    int start = b * CSR_CAP + sScan[t] - pad;   // exclusive scan; multiple of 8
    int node = (b << 8) + t;
    if (node < N) {
        se[node] = make_int2(start, start + pad);  // loop extent = padded
        dinv[node] = rsqrtf((float)c + 1.0f);      // true degree (+1 self-loop)
    }
    __syncthreads();
    sCnt[t] = start;                         // reuse as cursor
    __syncthreads();
    for (int i = t; i < m; i += 256) {
        unsigned p = sEdges[i];
        int pos = atomicAdd(&sCnt[p & 255u], 1);
        csr[pos] = (int)(p >> 16);           // src
    }
    // sentinel-fill pad slots (dinv[N]=0 -> zero contribution)
    if (node < N) {
        for (int k = start + c; k < start + pad; k++) csr[k] = N;
    }
}

// ---------------- K3: agg128 (pipelined, scalarized) + fused gemm2 ----------------
// Block = 16 nodes, wave = 4 nodes (serial). Stash relu'd bf16 rows in a
// block-shared 16x132 LDS tile -> syncthreads -> gemm2 split by octile:
// wave w computes oc-tile w (4 MFMA, K=128), scales dinv[row], stores h2s.
#define ACC8()                                             \
    do {                                                   \
        a0x += bflo(v0) * w0; a0y += bfhi(v0) * w0;        \
        a1x += bflo(v1) * w1; a1y += bfhi(v1) * w1;        \
        a2x += bflo(v2) * w2; a2y += bfhi(v2) * w2;        \
        a3x += bflo(v3) * w3; a3y += bfhi(v3) * w3;        \
        a0x += bflo(v4) * w4; a0y += bfhi(v4) * w4;        \
        a1x += bflo(v5) * w5; a1y += bfhi(v5) * w5;        \
        a2x += bflo(v6) * w6; a2y += bfhi(v6) * w6;        \
        a3x += bflo(v7) * w7; a3y += bfhi(v7) * w7;        \
    } while (0)

__global__ __launch_bounds__(256) void agg128_gemm2_kernel(
    const __bf16* __restrict__ h, const int* __restrict__ csr,
    const int2* __restrict__ se, const float* __restrict__ dinv,
    const float* __restrict__ bias, const bf16x8* __restrict__ wf2,
    __bf16* __restrict__ h2s, int N) {
    __shared__ __bf16 stash[16 * 132];    // 16 rows x 132(pad) bf16 = 4.2 KB
    int wave = threadIdx.x >> 6, lane = threadIdx.x & 63;
    int n0 = blockIdx.x * 16;             // block's 16 nodes
    unsigned* stw = (unsigned*)stash;     // dword view, row stride 66 words

    float2 bv = ((const float2*)bias)[lane];
#pragma unroll 1
    for (int i = 0; i < 4; i++) {
        int n = n0 + wave * 4 + i;
        float ox = 0.f, oy = 0.f;
        if (n < N) {
            int2 s_e = se[n];
            int start = s_e.x, m = s_e.y - s_e.x;    // m % 8 == 0
            float dn = dinv[n];
            const unsigned* hp = (const unsigned*)h;  // 2 bf16/word, stride 64 words
            const int* sl = csr + start;              // 32B-aligned
            unsigned self = hp[(long)n * 64 + lane];
            float a0x = bflo(self) * dn, a0y = bfhi(self) * dn;  // *dn at end -> dinv^2
            float a1x = 0.f, a1y = 0.f, a2x = 0.f, a2y = 0.f, a3x = 0.f, a3y = 0.f;
            if (m > 0) {
                int4 c0 = *(const int4*)sl;
                int4 c1 = *(const int4*)(sl + 4);
                int i0 = __builtin_amdgcn_readfirstlane(c0.x);
                int i1 = __builtin_amdgcn_readfirstlane(c0.y);
                int i2 = __builtin_amdgcn_readfirstlane(c0.z);
                int i3 = __builtin_amdgcn_readfirstlane(c0.w);
                int i4 = __builtin_amdgcn_readfirstlane(c1.x);
                int i5 = __builtin_amdgcn_readfirstlane(c1.y);
                int i6 = __builtin_amdgcn_readfirstlane(c1.z);
                int i7 = __builtin_amdgcn_readfirstlane(c1.w);
                unsigned v0 = hp[(long)i0 * 64 + lane], v1 = hp[(long)i1 * 64 + lane];
                unsigned v2 = hp[(long)i2 * 64 + lane], v3 = hp[(long)i3 * 64 + lane];
                unsigned v4 = hp[(long)i4 * 64 + lane], v5 = hp[(long)i5 * 64 + lane];
                unsigned v6 = hp[(long)i6 * 64 + lane], v7 = hp[(long)i7 * 64 + lane];
                float w0 = dinv[i0], w1 = dinv[i1], w2 = dinv[i2], w3 = dinv[i3];
                float w4 = dinv[i4], w5 = dinv[i5], w6 = dinv[i6], w7 = dinv[i7];
                int4 d0 = *(const int4*)(sl + 8);   // safe over-read (se follows csr)
                int4 d1 = *(const int4*)(sl + 12);
                for (int j = 8; j < m; j += 8) {
                    int t0 = __builtin_amdgcn_readfirstlane(d0.x);
                    int t1 = __builtin_amdgcn_readfirstlane(d0.y);
                    int t2 = __builtin_amdgcn_readfirstlane(d0.z);
                    int t3 = __builtin_amdgcn_readfirstlane(d0.w);
                    int t4 = __builtin_amdgcn_readfirstlane(d1.x);
                    int t5 = __builtin_amdgcn_readfirstlane(d1.y);
                    int t6 = __builtin_amdgcn_readfirstlane(d1.z);
                    int t7 = __builtin_amdgcn_readfirstlane(d1.w);
                    unsigned u0 = hp[(long)t0 * 64 + lane], u1 = hp[(long)t1 * 64 + lane];
                    unsigned u2 = hp[(long)t2 * 64 + lane], u3 = hp[(long)t3 * 64 + lane];
                    unsigned u4 = hp[(long)t4 * 64 + lane], u5 = hp[(long)t5 * 64 + lane];
                    unsigned u6 = hp[(long)t6 * 64 + lane], u7 = hp[(long)t7 * 64 + lane];
                    float q0 = dinv[t0], q1 = dinv[t1], q2 = dinv[t2], q3 = dinv[t3];
                    float q4 = dinv[t4], q5 = dinv[t5], q6 = dinv[t6], q7 = dinv[t7];
                    d0 = *(const int4*)(sl + j + 8);
                    d1 = *(const int4*)(sl + j + 12);
                    ACC8();
                    v0 = u0; v1 = u1; v2 = u2; v3 = u3; v4 = u4; v5 = u5; v6 = u6; v7 = u7;
                    w0 = q0; w1 = q1; w2 = q2; w3 = q3; w4 = q4; w5 = q5; w6 = q6; w7 = q7;
                }
                ACC8();
            }
            ox = fmaxf((a0x + a1x + a2x + a3x) * dn + bv.x, 0.f);
            oy = fmaxf((a0y + a1y + a2y + a3y) * dn + bv.y, 0.f);
        }
        bf16x2 st = {(__bf16)ox, (__bf16)oy};  // invalid nodes stash zeros
        stw[(wave * 4 + i) * 66 + lane] = *(unsigned*)&st;  // conflict-free (measured 0)
    }
    __syncthreads();

    // gemm2 from LDS: rows = 16 stashed nodes (B), wave w -> octile w of wf2 (A)
    int col = lane & 15, q = lane >> 4;
    const __bf16* srow = stash + col * 132;
    f32x4 acc = (f32x4){0.f, 0.f, 0.f, 0.f};
#pragma unroll
    for (int ks = 0; ks < 4; ks++) {
        bf16x8 bb = *(const bf16x8*)(srow + ks * 32 + q * 8);
        bf16x8 a = wf2[(ks * 4 + wave) * 64 + lane];
        acc = __builtin_amdgcn_mfma_f32_16x16x32_bf16(a, bb, acc, 0, 0, 0);
    }
    int node = n0 + col;
    if (node < N) {
        float dn2 = dinv[node];
        bf16x4 v;
#pragma unroll
        for (int r = 0; r < 4; r++) v[r] = (__bf16)(acc[r] * dn2);
        *(bf16x4*)(h2s + (long)node * 64 + (wave * 16 + q * 4)) = v;
    }
}
#undef ACC8

// ---------------- K5: agg64 (h2s pre-scaled by dinv[row]; sentinel row = 0) ----------------
// self term: h2s[n] already carries dinv[n]; final *dn gives dinv^2 (no extra *dn).
#define ACC8B()                                                                            \
    do {                                                                                   \
        a0 += __uint_as_float((unsigned)v0 << 16); a1 += __uint_as_float((unsigned)v1 << 16); \
        a2 += __uint_as_float((unsigned)v2 << 16); a3 += __uint_as_float((unsigned)v3 << 16); \
        a0 += __uint_as_float((unsigned)v4 << 16); a1 += __uint_as_float((unsigned)v5 << 16); \
        a2 += __uint_as_float((unsigned)v6 << 16); a3 += __uint_as_float((unsigned)v7 << 16); \
    } while (0)

__global__ __launch_bounds__(256) void agg64_kernel(const __bf16* __restrict__ hs,
                                                    const int* __restrict__ csr,
                                                    const int2* __restrict__ se,
                                                    const float* __restrict__ dinv,
                                                    const float* __restrict__ bias,
                                                    float* __restrict__ outp, int N) {
    int gid = blockIdx.x * TPB + threadIdx.x;
    int n = gid >> 6, lane = gid & 63;
    if (n >= N) return;
    int2 s_e = se[n];
    int start = s_e.x, m = s_e.y - s_e.x;    // m % 8 == 0
    float dn = dinv[n];
    const unsigned short* hp = (const unsigned short*)hs;  // row stride 64
    const int* sl = csr + start;
    float a0 = __uint_as_float(((unsigned)hp[(long)n * 64 + lane]) << 16);
    float a1 = 0.f, a2 = 0.f, a3 = 0.f;
    if (m > 0) {
        int4 c0 = *(const int4*)sl;
        int4 c1 = *(const int4*)(sl + 4);
        int i0 = __builtin_amdgcn_readfirstlane(c0.x);
        int i1 = __builtin_amdgcn_readfirstlane(c0.y);
        int i2 = __builtin_amdgcn_readfirstlane(c0.z);
        int i3 = __builtin_amdgcn_readfirstlane(c0.w);
        int i4 = __builtin_amdgcn_readfirstlane(c1.x);
        int i5 = __builtin_amdgcn_readfirstlane(c1.y);
        int i6 = __builtin_amdgcn_readfirstlane(c1.z);
        int i7 = __builtin_amdgcn_readfirstlane(c1.w);
        unsigned short v0 = hp[(long)i0 * 64 + lane], v1 = hp[(long)i1 * 64 + lane];
        unsigned short v2 = hp[(long)i2 * 64 + lane], v3 = hp[(long)i3 * 64 + lane];
        unsigned short v4 = hp[(long)i4 * 64 + lane], v5 = hp[(long)i5 * 64 + lane];
        unsigned short v6 = hp[(long)i6 * 64 + lane], v7 = hp[(long)i7 * 64 + lane];
        int4 d0 = *(const int4*)(sl + 8);
        int4 d1 = *(const int4*)(sl + 12);
        for (int j = 8; j < m; j += 8) {
            int t0 = __builtin_amdgcn_readfirstlane(d0.x);
            int t1 = __builtin_amdgcn_readfirstlane(d0.y);
            int t2 = __builtin_amdgcn_readfirstlane(d0.z);
            int t3 = __builtin_amdgcn_readfirstlane(d0.w);
            int t4 = __builtin_amdgcn_readfirstlane(d1.x);
            int t5 = __builtin_amdgcn_readfirstlane(d1.y);
            int t6 = __builtin_amdgcn_readfirstlane(d1.z);
            int t7 = __builtin_amdgcn_readfirstlane(d1.w);
            unsigned short u0 = hp[(long)t0 * 64 + lane], u1 = hp[(long)t1 * 64 + lane];
            unsigned short u2 = hp[(long)t2 * 64 + lane], u3 = hp[(long)t3 * 64 + lane];
            unsigned short u4 = hp[(long)t4 * 64 + lane], u5 = hp[(long)t5 * 64 + lane];
            unsigned short u6 = hp[(long)t6 * 64 + lane], u7 = hp[(long)t7 * 64 + lane];
            d0 = *(const int4*)(sl + j + 8);
            d1 = *(const int4*)(sl + j + 12);
            ACC8B();
            v0 = u0; v1 = u1; v2 = u2; v3 = u3; v4 = u4; v5 = u5; v6 = u6; v7 = u7;
        }
        ACC8B();
    }
    outp[(long)n * 64 + lane] = (a0 + a1 + a2 + a3) * dn + bias[lane];
}
#undef ACC8B

static inline int cdiv(long a, long b) { return (int)((a + b - 1) / b); }

extern "C" void kernel_launch(void* const* d_in, const int* in_sizes, int n_in,
                              void* d_out, int out_size, void* d_ws, size_t ws_size,
                              hipStream_t stream) {
    const float* x  = (const float*)d_in[0];
    const int*   ei = (const int*)d_in[1];
    const float* W1 = (const float*)d_in[2];
    const float* b1 = (const float*)d_in[3];
    const float* W2 = (const float*)d_in[4];
    const float* b2 = (const float*)d_in[5];

    const int IN_C = 256;
    const int N = in_sizes[0] / IN_C;   // 50000
    const int E = in_sizes[1] / 2;      // 800000
    const int* src = ei;
    const int* dst = ei + E;

    char* w = (char*)d_ws;
    size_t off = 0;
    auto alloc = [&](size_t bytes) { void* p = w + off; off = (off + bytes + 255) & ~255ull; return p; };
    __bf16*   h1u  = (__bf16*)alloc((size_t)(N + 1) * 128 * 2); // +sentinel row
    __bf16*   h2s  = (__bf16*)alloc((size_t)(N + 1) * 64 * 2);  // +sentinel row (zeroed)
    unsigned* ebuf = (unsigned*)alloc((size_t)NBKT * EB_CAP * 4);
    int*      csr  = (int*)alloc((size_t)NBKT * CSR_CAP * 4);
    int2*     se   = (int2*)alloc((size_t)N * 8);
    float*    dinv = (float*)alloc((size_t)(N + 1) * 4);        // +sentinel 0
    unsigned* gcnt = (unsigned*)alloc(NBKT * 4);
    __bf16*   wf1  = (__bf16*)alloc(64 * 64 * 8 * 2);
    __bf16*   wf2  = (__bf16*)alloc(16 * 64 * 8 * 2);

    // K0: clear bucket counters + sentinel rows (block 0) + pack W frags
    int wprepBlocks = cdiv(64 * 64 + 16 * 64, TPB);  // 20
    clear_wprep_kernel<<<1 + wprepBlocks, TPB, 0, stream>>>(gcnt, dinv, h2s, N,
                                                            W1, W2, wf1, wf2);

    // K1: bucket scatter (LDS two-pass) | gemm1 (h1u = x @ W1, unscaled)
    int p1Blocks = cdiv(E, P1_EPB);                  // 98
    int gemmBlocks = cdiv(N, 128);                   // 391
    p1_gemm1_kernel<<<p1Blocks + gemmBlocks, TPB, 0, stream>>>(
        src, dst, E, p1Blocks, gcnt, ebuf, x, (const bf16x8*)wf1, h1u, N);

    // K2: per-bucket dense CSR + dinv + (start, start+pad), sentinel-padded
    csr_kernel<<<NBKT, TPB, 0, stream>>>(gcnt, ebuf, csr, se, dinv, N);

    // K3: layer-1 aggregate (+bias, relu) fused with gemm2 -> h2s
    agg128_gemm2_kernel<<<cdiv(N, 16), TPB, 0, stream>>>(h1u, csr, se, dinv, b1,
                                                         (const bf16x8*)wf2, h2s, N);

    // K5: layer-2 aggregate -> d_out (fp32)
    agg64_kernel<<<cdiv((long)N * 64, TPB), TPB, 0, stream>>>(h2s, csr, se, dinv, b2,
                                                              (float*)d_out, N);
}